// Round 1
// baseline (215.133 us; speedup 1.0000x reference)
//
#include <hip/hip_runtime.h>

#define EPSF 1e-5f
#define NSEG 2048
#define LDST 136  // padded LDS row stride in bf16 elems (272B -> conflict-free b128 frag reads)

typedef short s16x8 __attribute__((ext_vector_type(8)));
typedef float f32x16 __attribute__((ext_vector_type(16)));

__device__ __forceinline__ unsigned short f2bf(float f) {
  unsigned int u = __float_as_uint(f);
  u += 0x7FFFu + ((u >> 16) & 1u);  // RNE; data has no NaN/Inf
  return (unsigned short)(u >> 16);
}
__device__ __forceinline__ float bf2f(unsigned short h) {
  return __uint_as_float(((unsigned int)h) << 16);
}

struct LayerP { const float *W, *b, *g, *be, *m, *v; };

// Fold BN into weights: W'[c,k] = W[c,k]*s_c (bf16), bias'_c = b_c*s_c + be_c - m_c*s_c
__global__ void prep_kernel(LayerP p0, LayerP p1, LayerP p2,
                            unsigned short* __restrict__ wsW,
                            float* __restrict__ biasf) {
  const int L = blockIdx.x;
  LayerP p = (L == 0) ? p0 : ((L == 1) ? p1 : p2);
  const int t = threadIdx.x;
  uint2* wdst = (uint2*)(wsW + L * 16384);
  const float4* wsrc = (const float4*)p.W;
  for (int i = 0; i < 16; ++i) {
    int idx4 = t + i * 256;            // 4096 float4 = 128x128
    int c = idx4 >> 5;                 // 32 float4 per row
    float s = p.g[c] * rsqrtf(p.v[c] + EPSF);
    float4 w = wsrc[idx4];
    unsigned lo = (unsigned)f2bf(w.x * s) | ((unsigned)f2bf(w.y * s) << 16);
    unsigned hi = (unsigned)f2bf(w.z * s) | ((unsigned)f2bf(w.w * s) << 16);
    wdst[idx4] = make_uint2(lo, hi);
  }
  if (t < 128) {
    float s = p.g[t] * rsqrtf(p.v[t] + EPSF);
    biasf[L * 128 + t] = p.b[t] * s + p.be[t] - p.m[t] * s;
  }
}

// Fused: x-tile(64 rows) -> 3x [GEMM(128x128) + bias + ReLU] in LDS -> segment sum/max/cnt atomics
__global__ __launch_bounds__(256)
void enc_kernel(const float* __restrict__ x, const int* __restrict__ batch,
                const unsigned short* __restrict__ wsW,
                const float* __restrict__ biasf,
                float* __restrict__ seg_sum, unsigned* __restrict__ seg_max,
                unsigned* __restrict__ seg_cnt, int N) {
  __shared__ __attribute__((aligned(16))) unsigned short in_tile[64 * LDST];
  __shared__ __attribute__((aligned(16))) unsigned short w_tile[128 * LDST];
  __shared__ __attribute__((aligned(16))) float bias_lds[128];
  __shared__ int sb[64];

  const int t = threadIdx.x;
  const int R0 = blockIdx.x * 64;
  if (t < 64) sb[t] = (R0 + t < N) ? batch[R0 + t] : -1;

  // stage x tile: fp32 -> bf16 -> LDS (padded rows)
  {
    const float4* xs = (const float4*)x;
    for (int i = 0; i < 8; ++i) {
      int f = t + i * 256;             // 2048 float4 = 64x128
      int row = f >> 5;
      int c4 = (f & 31) << 2;
      int r = R0 + row;
      float4 v = make_float4(0.f, 0.f, 0.f, 0.f);
      if (r < N) v = xs[(size_t)r * 32 + (f & 31)];
      unsigned lo = (unsigned)f2bf(v.x) | ((unsigned)f2bf(v.y) << 16);
      unsigned hi = (unsigned)f2bf(v.z) | ((unsigned)f2bf(v.w) << 16);
      *(uint2*)&in_tile[row * LDST + c4] = make_uint2(lo, hi);
    }
  }

  const int lane = t & 63, wv = t >> 6;
  const int lane31 = lane & 31, laneHi = lane >> 5;
  const int wm = wv & 1, wn = wv >> 1;   // wave grid: 2(ch) x 2(rows)
  const int brow = wn * 32 + lane31;     // x-row this lane consumes/produces

  for (int L = 0; L < 3; ++L) {
    __syncthreads();  // prev-layer reads of w_tile done; in_tile writes visible
    // stage W' bf16 into padded LDS
    const uint4* wsrc = (const uint4*)(wsW + L * 16384);
    for (int i = 0; i < 8; ++i) {
      int idx16 = t + i * 256;           // 2048 x 16B chunks
      int c = idx16 >> 4, k0 = (idx16 & 15) << 3;
      *(uint4*)&w_tile[c * LDST + k0] = wsrc[idx16];
    }
    if (t < 128) bias_lds[t] = biasf[L * 128 + t];
    __syncthreads();

    // C = W' @ X^T : A-frag from w_tile (M=ch), B-frag from in_tile (N=xrow)
    f32x16 acc0 = {0,0,0,0,0,0,0,0,0,0,0,0,0,0,0,0};
    f32x16 acc1 = {0,0,0,0,0,0,0,0,0,0,0,0,0,0,0,0};
    const int arow = wm * 64 + lane31;
#pragma unroll
    for (int kk = 0; kk < 128; kk += 16) {
      int ko = kk + laneHi * 8;
      s16x8 bfr = *(const s16x8*)&in_tile[brow * LDST + ko];
      s16x8 a0  = *(const s16x8*)&w_tile[arow * LDST + ko];
      s16x8 a1  = *(const s16x8*)&w_tile[(arow + 32) * LDST + ko];
      acc0 = __builtin_amdgcn_mfma_f32_32x32x16_bf16(a0, bfr, acc0, 0, 0, 0);
      acc1 = __builtin_amdgcn_mfma_f32_32x32x16_bf16(a1, bfr, acc1, 0, 0, 0);
    }
    __syncthreads();  // all in_tile reads done before overwrite

    // bias + ReLU, pack bf16, write back to in_tile
    // C/D layout: col(xrow) = lane&31, row(ch) = (reg&3) + 8*(reg>>2) + 4*(lane>>5)
#pragma unroll
    for (int mt = 0; mt < 2; ++mt) {
      const f32x16 A = mt ? acc1 : acc0;
      int chb = wm * 64 + mt * 32 + 4 * laneHi;
#pragma unroll
      for (int g = 0; g < 4; ++g) {
        int ch = chb + 8 * g;
        float4 bb = *(const float4*)&bias_lds[ch];
        float v0 = fmaxf(A[4 * g + 0] + bb.x, 0.f);
        float v1 = fmaxf(A[4 * g + 1] + bb.y, 0.f);
        float v2 = fmaxf(A[4 * g + 2] + bb.z, 0.f);
        float v3 = fmaxf(A[4 * g + 3] + bb.w, 0.f);
        unsigned lo = (unsigned)f2bf(v0) | ((unsigned)f2bf(v1) << 16);
        unsigned hi = (unsigned)f2bf(v2) | ((unsigned)f2bf(v3) << 16);
        *(uint2*)&in_tile[brow * LDST + ch] = make_uint2(lo, hi);
      }
    }
  }
  __syncthreads();  // h3 in LDS

  // per-segment counts (one atomic per run; batch sorted)
  if (t < 64) {
    int seg = sb[t];
    if (seg >= 0 && (t == 0 || sb[t - 1] != seg)) {
      int e = t + 1;
      while (e < 64 && sb[e] == seg) ++e;
      atomicAdd(&seg_cnt[seg], (unsigned)(e - t));
    }
  }

  // segment sum/max: wave q owns rows [16q,16q+16), lane owns col-pair 2*lane
  {
    int cp = (t & 63) * 2;
    int q = t >> 6;
    float s0 = 0.f, s1 = 0.f, m0 = 0.f, m1 = 0.f;
    int cur = sb[q * 16];
    for (int r = q * 16; r < q * 16 + 16; ++r) {
      int seg = sb[r];
      if (seg != cur) {
        if (cur >= 0) {
          if (s0 != 0.f || m0 != 0.f) { atomicAdd(&seg_sum[cur * 128 + cp], s0); atomicMax((int*)&seg_max[cur * 128 + cp], __float_as_int(m0)); }
          if (s1 != 0.f || m1 != 0.f) { atomicAdd(&seg_sum[cur * 128 + cp + 1], s1); atomicMax((int*)&seg_max[cur * 128 + cp + 1], __float_as_int(m1)); }
        }
        s0 = s1 = m0 = m1 = 0.f;
        cur = seg;
      }
      if (seg >= 0) {
        unsigned pv = *(const unsigned*)&in_tile[r * LDST + cp];
        float v0 = bf2f((unsigned short)(pv & 0xffffu));
        float v1 = bf2f((unsigned short)(pv >> 16));
        s0 += v0; s1 += v1;
        m0 = fmaxf(m0, v0); m1 = fmaxf(m1, v1);
      }
    }
    if (cur >= 0) {
      if (s0 != 0.f || m0 != 0.f) { atomicAdd(&seg_sum[cur * 128 + cp], s0); atomicMax((int*)&seg_max[cur * 128 + cp], __float_as_int(m0)); }
      if (s1 != 0.f || m1 != 0.f) { atomicAdd(&seg_sum[cur * 128 + cp + 1], s1); atomicMax((int*)&seg_max[cur * 128 + cp + 1], __float_as_int(m1)); }
    }
  }
}

// out[s,o] = BN( [sum|max|mean] @ Wo^T + bo )
__global__ __launch_bounds__(128)
void proj_kernel(const float* __restrict__ seg_sum, const unsigned* __restrict__ seg_max,
                 const unsigned* __restrict__ seg_cnt,
                 const float* __restrict__ Wo, const float* __restrict__ bo,
                 const float* __restrict__ go, const float* __restrict__ beo,
                 const float* __restrict__ mo, const float* __restrict__ vo,
                 float* __restrict__ out) {
  __shared__ __attribute__((aligned(16))) float agg[384];
  __shared__ float part[64];
  const int s = blockIdx.x, t = threadIdx.x;
  float cinv = 1.f / fmaxf((float)seg_cnt[s], 1.f);
  for (int i = t; i < 384; i += 128) {
    float v;
    if (i < 128)      v = seg_sum[s * 128 + i];
    else if (i < 256) v = __uint_as_float(seg_max[s * 128 + i - 128]);
    else              v = seg_sum[s * 128 + i - 256] * cinv;
    agg[i] = v;
  }
  __syncthreads();
  const int o = t & 63, hf = t >> 6;
  const float4* wrow = (const float4*)(Wo + o * 384 + hf * 192);
  float acc = 0.f;
#pragma unroll 8
  for (int k4 = 0; k4 < 48; ++k4) {
    float4 w = wrow[k4];
    float4 a = *(const float4*)&agg[hf * 192 + k4 * 4];
    acc += w.x * a.x + w.y * a.y + w.z * a.z + w.w * a.w;
  }
  if (hf) part[o] = acc;
  __syncthreads();
  if (!hf) {
    acc += part[o];
    float sc = go[o] * rsqrtf(vo[o] + EPSF);
    out[s * 64 + o] = (acc + bo[o] - mo[o]) * sc + beo[o];
  }
}

extern "C" void kernel_launch(void* const* d_in, const int* in_sizes, int n_in,
                              void* d_out, int out_size, void* d_ws, size_t ws_size,
                              hipStream_t stream) {
  (void)n_in; (void)out_size; (void)ws_size;
  const float* x = (const float*)d_in[0];
  const int* batch = (const int*)d_in[1];
  LayerP P0{(const float*)d_in[2],  (const float*)d_in[3],  (const float*)d_in[4],
            (const float*)d_in[5],  (const float*)d_in[6],  (const float*)d_in[7]};
  LayerP P1{(const float*)d_in[8],  (const float*)d_in[9],  (const float*)d_in[10],
            (const float*)d_in[11], (const float*)d_in[12], (const float*)d_in[13]};
  LayerP P2{(const float*)d_in[14], (const float*)d_in[15], (const float*)d_in[16],
            (const float*)d_in[17], (const float*)d_in[18], (const float*)d_in[19]};
  const float* Wo  = (const float*)d_in[20];
  const float* bo  = (const float*)d_in[21];
  const float* go  = (const float*)d_in[22];
  const float* beo = (const float*)d_in[23];
  const float* mo  = (const float*)d_in[24];
  const float* vo  = (const float*)d_in[25];
  const int N = in_sizes[0] / 128;

  char* ws = (char*)d_ws;
  float*    seg_sum = (float*)ws;                          // 2048*128 f32 = 1 MiB
  unsigned* seg_max = (unsigned*)(ws + (1u << 20));        // 1 MiB (float bits, >=0)
  unsigned* seg_cnt = (unsigned*)(ws + (2u << 20));        // 8 KiB
  unsigned short* wsW = (unsigned short*)(ws + (2u << 20) + 8192);      // 3*128*128 bf16
  float* biasf = (float*)(ws + (2u << 20) + 8192 + 98304);              // 3*128 f32

  hipMemsetAsync(d_ws, 0, (size_t)(2u << 20) + 8192, stream);
  prep_kernel<<<3, 256, 0, stream>>>(P0, P1, P2, wsW, biasf);
  const int nblk = (N + 63) / 64;
  enc_kernel<<<nblk, 256, 0, stream>>>(x, batch, wsW, biasf, seg_sum, seg_max, seg_cnt, N);
  proj_kernel<<<NSEG, 128, 0, stream>>>(seg_sum, seg_max, seg_cnt, Wo, bo, go, beo, mo, vo,
                                        (float*)d_out);
}